// Round 7
// baseline (282.033 us; speedup 1.0000x reference)
//
#include <hip/hip_runtime.h>
#include <type_traits>

// ---------- types ----------
typedef short s8v   __attribute__((ext_vector_type(8)));   // 8 x bf16 bits
typedef float f32x4 __attribute__((ext_vector_type(4)));
typedef float f32x16 __attribute__((ext_vector_type(16)));
typedef unsigned int u32x2 __attribute__((ext_vector_type(2)));
typedef unsigned int u32x4 __attribute__((ext_vector_type(4)));

__device__ __forceinline__ unsigned short f2bf(float f) {
    unsigned int u = __builtin_bit_cast(unsigned int, f);
    u += 0x7FFF + ((u >> 16) & 1);          // round-to-nearest-even
    return (unsigned short)(u >> 16);
}
__device__ __forceinline__ float bf2f(unsigned short b) {
    unsigned int u = ((unsigned int)b) << 16;
    return __builtin_bit_cast(float, u);
}
__device__ __forceinline__ unsigned int cvtpk(float lo, float hi) {
    unsigned int w;
    asm("v_cvt_pk_bf16_f32 %0, %1, %2" : "=v"(w) : "v"(lo), "v"(hi));
    return w;
}

__device__ __forceinline__ void gload16(const void* g, void* l) {
    __builtin_amdgcn_global_load_lds(
        (const __attribute__((address_space(1))) void*)g,
        (__attribute__((address_space(3))) void*)l, 16, 0, 0);
}

// ---------- x -> bf16 (vectorized) ----------
__global__ void conv_bf16(const float* __restrict__ src, unsigned short* __restrict__ dst, int n8) {
    int i = blockIdx.x * blockDim.x + threadIdx.x;
    if (i >= n8) return;
    const f32x4* s4 = (const f32x4*)src;
    f32x4 a = s4[2 * i], b = s4[2 * i + 1];
    s8v o;
    o[0] = (short)f2bf(a[0]); o[1] = (short)f2bf(a[1]);
    o[2] = (short)f2bf(a[2]); o[3] = (short)f2bf(a[3]);
    o[4] = (short)f2bf(b[0]); o[5] = (short)f2bf(b[1]);
    o[6] = (short)f2bf(b[2]); o[7] = (short)f2bf(b[3]);
    *(s8v*)(dst + (size_t)i * 8) = o;
}

// ---------- W (KxN f32) -> W^T (NxK bf16), single weight ----------
__global__ void transpose_conv(const float* __restrict__ src, unsigned short* __restrict__ dst,
                               int K, int N) {
    __shared__ float tile[32][33];
    int n0 = blockIdx.x * 32, k0 = blockIdx.y * 32;
    int tx = threadIdx.x, ty = threadIdx.y;     // 32 x 8
#pragma unroll
    for (int r = 0; r < 4; ++r)
        tile[ty + r * 8][tx] = src[(size_t)(k0 + ty + r * 8) * N + n0 + tx];
    __syncthreads();
#pragma unroll
    for (int r = 0; r < 4; ++r)
        dst[(size_t)(n0 + ty + r * 8) * K + k0 + tx] = f2bf(tile[tx][ty + r * 8]);
}

// ---------- wq/wk/wv -> fused W^T [3072][2048] bf16, one launch ----------
__global__ void transpose_conv_qkv(const float* __restrict__ wq, const float* __restrict__ wk,
                                   const float* __restrict__ wv, unsigned short* __restrict__ dst) {
    __shared__ float tile[32][33];
    int n0 = blockIdx.x * 32, k0 = blockIdx.y * 32;   // n0: 0..3071 (out row), k0: 0..2047
    const float* src; int sc, N;
    if (n0 < 2048)      { src = wq; sc = n0;        N = 2048; }
    else if (n0 < 2560) { src = wk; sc = n0 - 2048; N = 512;  }
    else                { src = wv; sc = n0 - 2560; N = 512;  }
    int tx = threadIdx.x, ty = threadIdx.y;     // 32 x 8
#pragma unroll
    for (int r = 0; r < 4; ++r)
        tile[ty + r * 8][tx] = src[(size_t)(k0 + ty + r * 8) * N + sc + tx];
    __syncthreads();
#pragma unroll
    for (int r = 0; r < 4; ++r)
        dst[(size_t)(n0 + ty + r * 8) * 2048 + k0 + tx] = f2bf(tile[tx][ty + r * 8]);
}

// ---------- V (cols 2560..3071 of qkv) -> V^T [b][kvh][128][2048] bf16 ----------
__global__ void vtrans(const unsigned short* __restrict__ qkv, unsigned short* __restrict__ vt) {
    __shared__ unsigned short t[32][33];
    int s0 = blockIdx.x * 32;          // global row 0..4095
    int c0 = blockIdx.y * 32;          // v-col 0..511
    int tx = threadIdx.x, ty = threadIdx.y;   // 32 x 8
#pragma unroll
    for (int r = 0; r < 4; ++r)
        t[ty + r * 8][tx] = qkv[(size_t)(s0 + ty + r * 8) * 3072 + 2560 + c0 + tx];
    __syncthreads();
    int b = s0 >> 11, s = s0 & 2047;
    size_t dbase = (size_t)(b * 4 + (c0 >> 7)) * 128 + (c0 & 127);
#pragma unroll
    for (int r = 0; r < 4; ++r)
        vt[(dbase + ty + r * 8) * 2048 + s + tx] = t[tx][ty + r * 8];
}

// ---------- GEMM: C(MxN) = A(MxK,bf16) * B^T(NxK,bf16), m97 structure ----------
// ROPE: fuse rotary embedding into the epilogue (pairs (c, c^1) live in lanes (lane, lane^1)).
template <typename CT, bool ROPE>
__global__ __launch_bounds__(256)
void gemm_bt(const unsigned short* __restrict__ A, const unsigned short* __restrict__ BT,
             CT* __restrict__ C, const float* __restrict__ fc, const float* __restrict__ fs,
             int M, int N, int K, int ldc) {
    __shared__ unsigned short As[128 * 32];
    __shared__ unsigned short Bs[128 * 32];
    const int tid = threadIdx.x;
    const int wid = tid >> 6, lane = tid & 63;
    const int lr = lane & 15, lg = lane >> 4;
    const int brow = blockIdx.y * 128, bcol = blockIdx.x * 128;
    const int wr = wid >> 1, wc = wid & 1;      // 2x2 waves, 64x64 each
    f32x4 acc[4][4] = {};

    for (int kt = 0; kt < K; kt += 32) {
#pragma unroll
        for (int i = 0; i < 2; ++i) {
            int f = i * 256 + tid;              // unit of 8 elems
            int row = f >> 2;
            int col8 = (f & 3) << 3;
            gload16(A + (size_t)(brow + row) * K + kt + col8,
                    As + (size_t)(i * 256 + wid * 64) * 8);
            gload16(BT + (size_t)(bcol + row) * K + kt + col8,
                    Bs + (size_t)(i * 256 + wid * 64) * 8);
        }
        __syncthreads();
        s8v a[4], b[4];
#pragma unroll
        for (int m = 0; m < 4; ++m)
            a[m] = *(const s8v*)(As + (size_t)(wr * 64 + m * 16 + lr) * 32 + lg * 8);
#pragma unroll
        for (int n = 0; n < 4; ++n)
            b[n] = *(const s8v*)(Bs + (size_t)(wc * 64 + n * 16 + lr) * 32 + lg * 8);
#pragma unroll
        for (int m = 0; m < 4; ++m)
#pragma unroll
            for (int n = 0; n < 4; ++n)
                acc[m][n] = __builtin_amdgcn_mfma_f32_16x16x32_bf16(a[m], b[n], acc[m][n], 0, 0, 0);
        __syncthreads();
    }
#pragma unroll
    for (int m = 0; m < 4; ++m)
#pragma unroll
        for (int n = 0; n < 4; ++n)
#pragma unroll
            for (int j = 0; j < 4; ++j) {
                int r = brow + wr * 64 + m * 16 + lg * 4 + j;
                int c = bcol + wc * 64 + n * 16 + lr;
                float v = acc[m][n][j];
                if constexpr (ROPE) {
                    // q cols [0,2048), k cols [2048,2560): rotate pairs (c even, c+1)
                    float vp = __shfl_xor(v, 1);
                    if (c < 2560) {
                        int fi = ((r & 2047) << 6) + ((c & 127) >> 1);
                        float cs = fc[fi], sn = fs[fi];
                        v = (lr & 1) ? (vp * sn + v * cs) : (v * cs - vp * sn);
                    }
                }
                if constexpr (std::is_same<CT, float>::value)
                    C[(size_t)r * ldc + c] = v;
                else
                    C[(size_t)r * ldc + c] = f2bf(v);
            }
}

// ---------- Flash attention, GQA, causal — 32x32 MFMA, LDS-staged KV, lane-local softmax --
// 512 blocks x 256 threads (4 waves). blockIdx&7 = (b,kvh) -> XCD-pinned KV (1MB/XCD L2).
// The 4 waves are the 4 q-heads sharing this kvh: ONE staged K/V tile feeds 4 heads.
// Balanced pairing: CU gets blocks k and k+32 (dispatch rounds 1 and 2) whose tile
// counts sum to a constant 33 -> qi = (k<32) ? 63-k : k-32.
// Each wave owns 32 q rows (q = qw + lane&31); swapped 32x32 QK^T keeps q lane-local
// (softmax/rescale/normalize lane-local; P->B-frag = 16 cvt_pk + 8 shfl_xor(32)).
// K and V^T staged via coalesced global_load_lds, both-sides XOR swizzle (rule 21)
// -> conflict-free ds_read_b128 fragment reads. KVBLK=64 double-buffered (64KB LDS).
__global__ __launch_bounds__(256)
void attn_kernel(const unsigned short* __restrict__ qkv,
                 const unsigned short* __restrict__ vtg,
                 unsigned short* __restrict__ out) {
    constexpr int S = 2048;
    __shared__ unsigned short Ks[2][64 * 128];   // [key][d-unit8 ^ (key&7)]
    __shared__ unsigned short Vs[2][128 * 64];   // [d][key-unit8 ^ (d&7)]
    const int tid = threadIdx.x, lane = tid & 63, wid = tid >> 6;
    const int l31 = lane & 31, h2 = lane >> 5;
    const int lsw = l31 & 7;
    const int g8 = blockIdx.x & 7;               // (b,kvh) -> XCD pin
    const int b = g8 >> 2, kvh = g8 & 3;
    const int k = blockIdx.x >> 3;
    const int qi = (k < 32) ? (63 - k) : (k - 32);   // balanced CU pairing (33 tiles/CU)
    const int h = kvh * 4 + wid;                 // wave = head
    const int qw = qi * 32;
    const int qq = qw + l31;                     // this lane's q row
    const size_t rs = 3072;
    const float rscale = 0.08838834764831845f;   // 1/sqrt(128)

    const unsigned short* Qp = qkv + (size_t)(b * S + qw) * rs + h * 128 + h2 * 8;
    const unsigned short* Kbase = qkv + (size_t)(b * S) * rs + 2048 + kvh * 128;
    const unsigned short* Vtg = vtg + (size_t)((b * 4 + kvh) * 128) * S;

    // Q B-frag: col=q=l31, k = 16*kk + 8*h2 + e  (scattered, but once per kernel)
    s8v qf[8];
#pragma unroll
    for (int kk = 0; kk < 8; ++kk)
        qf[kk] = *(const s8v*)(Qp + (size_t)l31 * rs + kk * 16);

    f32x16 acc[4] = {};                          // out^T: acc[dblk], row d, col q
    float m_run = -1e30f, l_run = 0.f;
    const int nt = (qi >> 1) + 1;

    auto stage = [&](int t, int bufi) {
        const int kb64 = t * 64;
#pragma unroll
        for (int i = 0; i < 4; ++i) {            // K tile [64][128]: 1024 chunks of 16B
            int c = i * 256 + tid;
            int key = c >> 4, d8 = c & 15;
            gload16(Kbase + (size_t)(kb64 + key) * rs + ((d8 ^ (key & 7)) << 3),
                    &Ks[bufi][(size_t)c * 8]);
        }
#pragma unroll
        for (int i = 0; i < 4; ++i) {            // V^T tile [128][64]
            int c = i * 256 + tid;
            int d = c >> 3, k8 = c & 7;
            gload16(Vtg + (size_t)d * S + kb64 + ((k8 ^ (d & 7)) << 3),
                    &Vs[bufi][(size_t)c * 8]);
        }
    };

    int cur = 0;
    stage(0, 0);
    __syncthreads();

    for (int t = 0; t < nt; ++t) {
        if (t + 1 < nt) stage(t + 1, cur ^ 1);
        const int kb64 = t * 64;
        const char* Kb = (const char*)&Ks[cur][0];
        const char* Vb = (const char*)&Vs[cur][0];

        // ---- K A-frags from LDS (row=key, k=16kk+8h2+e); conflict-free swizzled ----
        s8v kf0[8], kf1[8];
#pragma unroll
        for (int kk = 0; kk < 8; ++kk)
            kf0[kk] = *(const s8v*)(Kb + l31 * 256 + (((2 * kk + h2) ^ lsw) << 4));
#pragma unroll
        for (int kk = 0; kk < 8; ++kk)
            kf1[kk] = *(const s8v*)(Kb + (32 + l31) * 256 + (((2 * kk + h2) ^ lsw) << 4));
        // ---- V^T A-frags (row=d=32dblk+l31, k=key=16kb+8h2+e) ----
        s8v vf[4][4];
#pragma unroll
        for (int kb = 0; kb < 4; ++kb)
#pragma unroll
            for (int dblk = 0; dblk < 4; ++dblk)
                vf[kb][dblk] = *(const s8v*)(Vb + (32 * dblk + l31) * 128 +
                                             (((2 * kb + h2) ^ lsw) << 4));

        // ---- QK^T (swapped): S^T[key][q], C col = q lane-local ----
        f32x16 sacc0 = {}, sacc1 = {};
        __builtin_amdgcn_s_setprio(1);
#pragma unroll
        for (int kk = 0; kk < 8; ++kk)
            sacc0 = __builtin_amdgcn_mfma_f32_32x32x16_bf16(kf0[kk], qf[kk], sacc0, 0, 0, 0);
#pragma unroll
        for (int kk = 0; kk < 8; ++kk)
            sacc1 = __builtin_amdgcn_mfma_f32_32x32x16_bf16(kf1[kk], qf[kk], sacc1, 0, 0, 0);
        __builtin_amdgcn_s_setprio(0);

        // ---- mask + scale: lane holds S[key(r,g)][q=qq] ----
        float sv[32];
#pragma unroll
        for (int g = 0; g < 2; ++g)
#pragma unroll
            for (int r = 0; r < 16; ++r) {
                int key = kb64 + 32 * g + (r & 3) + 8 * (r >> 2) + 4 * h2;
                float s = (g ? sacc1[r] : sacc0[r]) * rscale;
                sv[g * 16 + r] = (key <= qq) ? s : -1e30f;
            }

        // ---- online softmax, q lane-local; defer-max (THR=8) ----
        float mx = sv[0];
#pragma unroll
        for (int i = 1; i < 32; ++i) mx = fmaxf(mx, sv[i]);
        mx = fmaxf(mx, __shfl_xor(mx, 32));
        if (!__all(mx - m_run <= 8.f)) {
            float mn = fmaxf(m_run, mx);
            float alpha = __expf(m_run - mn);
            m_run = mn;
            l_run *= alpha;
#pragma unroll
            for (int dblk = 0; dblk < 4; ++dblk)
#pragma unroll
                for (int r = 0; r < 16; ++r) acc[dblk][r] *= alpha;
        }
        float ps = 0.f;
#pragma unroll
        for (int i = 0; i < 32; ++i) {
            float e = __expf(sv[i] - m_run);
            sv[i] = e;
            ps += e;
        }
        ps += __shfl_xor(ps, 32);
        l_run += ps;

        // ---- P -> B-frag (col=q, k=key): cvt_pk pairs + lane^32 exchange ----
        unsigned int pw[4][4];
#pragma unroll
        for (int g = 0; g < 2; ++g) {
            unsigned int w[8];
#pragma unroll
            for (int j = 0; j < 8; ++j)
                w[j] = cvtpk(sv[g * 16 + 2 * j], sv[g * 16 + 2 * j + 1]);
#pragma unroll
            for (int u = 0; u < 2; ++u) {
                unsigned int t0 = (unsigned)__shfl_xor((int)w[4 * u + 0], 32);
                unsigned int t1 = (unsigned)__shfl_xor((int)w[4 * u + 1], 32);
                unsigned int t2 = (unsigned)__shfl_xor((int)w[4 * u + 2], 32);
                unsigned int t3 = (unsigned)__shfl_xor((int)w[4 * u + 3], 32);
                pw[2 * g + u][0] = h2 ? t2 : w[4 * u + 0];
                pw[2 * g + u][1] = h2 ? t3 : w[4 * u + 1];
                pw[2 * g + u][2] = h2 ? w[4 * u + 2] : t0;
                pw[2 * g + u][3] = h2 ? w[4 * u + 3] : t1;
            }
        }

        // ---- PV: out^T[d][q] += V^T(32d x 16k) * P^T(16k x 32q) ----
        __builtin_amdgcn_s_setprio(1);
#pragma unroll
        for (int kb = 0; kb < 4; ++kb) {
            u32x4 wv;
            wv[0] = pw[kb][0]; wv[1] = pw[kb][1]; wv[2] = pw[kb][2]; wv[3] = pw[kb][3];
            s8v pf = __builtin_bit_cast(s8v, wv);
#pragma unroll
            for (int dblk = 0; dblk < 4; ++dblk)
                acc[dblk] = __builtin_amdgcn_mfma_f32_32x32x16_bf16(vf[kb][dblk], pf, acc[dblk], 0, 0, 0);
        }
        __builtin_amdgcn_s_setprio(0);

        __syncthreads();
        cur ^= 1;
    }

    // ---- normalize (lane-local) and store out[q][h*128+d] ----
    float inv = 1.f / l_run;
    unsigned short* Op = out + (size_t)(b * S + qq) * 2048 + h * 128 + 4 * h2;
#pragma unroll
    for (int dblk = 0; dblk < 4; ++dblk)
#pragma unroll
        for (int s = 0; s < 4; ++s) {
            u32x2 wv;
            wv[0] = cvtpk(acc[dblk][4 * s + 0] * inv, acc[dblk][4 * s + 1] * inv);
            wv[1] = cvtpk(acc[dblk][4 * s + 2] * inv, acc[dblk][4 * s + 3] * inv);
            *(u32x2*)(Op + 32 * dblk + 8 * s) = wv;
        }
}

// ---------- launch ----------
extern "C" void kernel_launch(void* const* d_in, const int* in_sizes, int n_in,
                              void* d_out, int out_size, void* d_ws, size_t ws_size,
                              hipStream_t stream) {
    const float* x  = (const float*)d_in[0];
    const float* fc = (const float*)d_in[1];
    const float* fs = (const float*)d_in[2];
    const float* wq = (const float*)d_in[4];
    const float* wk = (const float*)d_in[5];
    const float* wv = (const float*)d_in[6];
    const float* wo = (const float*)d_in[7];
    float* out = (float*)d_out;

    char* ws = (char*)d_ws;
    unsigned short* xb    = (unsigned short*)ws;                               // 16 MB (reused as attn out)
    unsigned short* wqkvT = (unsigned short*)(ws + 16777216);                  // 12 MB (reused as V^T)
    unsigned short* woT   = (unsigned short*)(ws + 16777216 + 12582912);       // 8 MB
    unsigned short* qkvb  = (unsigned short*)(ws + 16777216 + 12582912 + 8388608); // 24 MB
    unsigned short* attnb = xb;
    unsigned short* vtb   = wqkvT;      // V^T [2][4][128][2048] = 4 MB, lives after gemm1

    conv_bf16<<<4096, 256, 0, stream>>>(x, xb, 1048576);
    dim3 tb(32, 8);
    transpose_conv_qkv<<<dim3(96, 64), tb, 0, stream>>>(wq, wk, wv, wqkvT);
    transpose_conv<<<dim3(64, 64), tb, 0, stream>>>(wo, woT, 2048, 2048);
    // gemm1 with fused RoPE on q/k columns (c < 2560)
    gemm_bt<unsigned short, true><<<dim3(24, 32), 256, 0, stream>>>(
        xb, wqkvT, qkvb, fc, fs, 4096, 3072, 2048, 3072);
    vtrans<<<dim3(128, 16), tb, 0, stream>>>(qkvb, vtb);
    attn_kernel<<<512, 256, 0, stream>>>(qkvb, vtb, attnb);
    gemm_bt<float, false><<<dim3(16, 32), 256, 0, stream>>>(
        attnb, woT, out, nullptr, nullptr, 4096, 2048, 2048, 2048);
}

// Round 8
// 239.969 us; speedup vs baseline: 1.1753x; 1.1753x over previous
//
#include <hip/hip_runtime.h>
#include <type_traits>

// ---------- types ----------
typedef short s8v   __attribute__((ext_vector_type(8)));   // 8 x bf16 bits
typedef float f32x4 __attribute__((ext_vector_type(4)));
typedef float f32x16 __attribute__((ext_vector_type(16)));
typedef unsigned int u32x2 __attribute__((ext_vector_type(2)));
typedef unsigned int u32x4 __attribute__((ext_vector_type(4)));

__device__ __forceinline__ unsigned short f2bf(float f) {
    unsigned int u = __builtin_bit_cast(unsigned int, f);
    u += 0x7FFF + ((u >> 16) & 1);          // round-to-nearest-even
    return (unsigned short)(u >> 16);
}
__device__ __forceinline__ float bf2f(unsigned short b) {
    unsigned int u = ((unsigned int)b) << 16;
    return __builtin_bit_cast(float, u);
}
__device__ __forceinline__ unsigned int cvtpk(float lo, float hi) {
    unsigned int w;
    asm("v_cvt_pk_bf16_f32 %0, %1, %2" : "=v"(w) : "v"(lo), "v"(hi));
    return w;
}

__device__ __forceinline__ void gload16(const void* g, void* l) {
    __builtin_amdgcn_global_load_lds(
        (const __attribute__((address_space(1))) void*)g,
        (__attribute__((address_space(3))) void*)l, 16, 0, 0);
}

// ---------- x -> bf16 (vectorized) ----------
__global__ void conv_bf16(const float* __restrict__ src, unsigned short* __restrict__ dst, int n8) {
    int i = blockIdx.x * blockDim.x + threadIdx.x;
    if (i >= n8) return;
    const f32x4* s4 = (const f32x4*)src;
    f32x4 a = s4[2 * i], b = s4[2 * i + 1];
    s8v o;
    o[0] = (short)f2bf(a[0]); o[1] = (short)f2bf(a[1]);
    o[2] = (short)f2bf(a[2]); o[3] = (short)f2bf(a[3]);
    o[4] = (short)f2bf(b[0]); o[5] = (short)f2bf(b[1]);
    o[6] = (short)f2bf(b[2]); o[7] = (short)f2bf(b[3]);
    *(s8v*)(dst + (size_t)i * 8) = o;
}

// ---------- W (KxN f32) -> W^T (NxK bf16), single weight ----------
__global__ void transpose_conv(const float* __restrict__ src, unsigned short* __restrict__ dst,
                               int K, int N) {
    __shared__ float tile[32][33];
    int n0 = blockIdx.x * 32, k0 = blockIdx.y * 32;
    int tx = threadIdx.x, ty = threadIdx.y;     // 32 x 8
#pragma unroll
    for (int r = 0; r < 4; ++r)
        tile[ty + r * 8][tx] = src[(size_t)(k0 + ty + r * 8) * N + n0 + tx];
    __syncthreads();
#pragma unroll
    for (int r = 0; r < 4; ++r)
        dst[(size_t)(n0 + ty + r * 8) * K + k0 + tx] = f2bf(tile[tx][ty + r * 8]);
}

// ---------- wq/wk/wv -> fused W^T [3072][2048] bf16, one launch ----------
__global__ void transpose_conv_qkv(const float* __restrict__ wq, const float* __restrict__ wk,
                                   const float* __restrict__ wv, unsigned short* __restrict__ dst) {
    __shared__ float tile[32][33];
    int n0 = blockIdx.x * 32, k0 = blockIdx.y * 32;   // n0: 0..3071 (out row), k0: 0..2047
    const float* src; int sc, N;
    if (n0 < 2048)      { src = wq; sc = n0;        N = 2048; }
    else if (n0 < 2560) { src = wk; sc = n0 - 2048; N = 512;  }
    else                { src = wv; sc = n0 - 2560; N = 512;  }
    int tx = threadIdx.x, ty = threadIdx.y;     // 32 x 8
#pragma unroll
    for (int r = 0; r < 4; ++r)
        tile[ty + r * 8][tx] = src[(size_t)(k0 + ty + r * 8) * N + sc + tx];
    __syncthreads();
#pragma unroll
    for (int r = 0; r < 4; ++r)
        dst[(size_t)(n0 + ty + r * 8) * 2048 + k0 + tx] = f2bf(tile[tx][ty + r * 8]);
}

// ---------- V (cols 2560..3071 of qkv) -> V^T [b][kvh][128][2048] bf16 ----------
__global__ void vtrans(const unsigned short* __restrict__ qkv, unsigned short* __restrict__ vt) {
    __shared__ unsigned short t[32][33];
    int s0 = blockIdx.x * 32;          // global row 0..4095
    int c0 = blockIdx.y * 32;          // v-col 0..511
    int tx = threadIdx.x, ty = threadIdx.y;   // 32 x 8
#pragma unroll
    for (int r = 0; r < 4; ++r)
        t[ty + r * 8][tx] = qkv[(size_t)(s0 + ty + r * 8) * 3072 + 2560 + c0 + tx];
    __syncthreads();
    int b = s0 >> 11, s = s0 & 2047;
    size_t dbase = (size_t)(b * 4 + (c0 >> 7)) * 128 + (c0 & 127);
#pragma unroll
    for (int r = 0; r < 4; ++r)
        vt[(dbase + ty + r * 8) * 2048 + s + tx] = t[tx][ty + r * 8];
}

// ---------- GEMM: C(MxN) = A(MxK,bf16) * B^T(NxK,bf16) ----------
// 128x128 tile, BK=64, 4 waves (2x2, each 64x64 as 2x2 of 32x32 MFMA frags).
// Staging via global_load_lds w/ unit-XOR swizzle (both-sides, rule 21).
// 32x32x16 MFMA: ~15% fewer MFMA-issue cycles than 16x16x32; A/B/C lane maps
// identical to the attn kernel's end-to-end-verified QK^T path.
// ROPE: fuse rotary embedding into the epilogue (pairs (c, c^1) in lanes (l31, l31^1)).
template <typename CT, bool ROPE>
__global__ __launch_bounds__(256)
void gemm_bt(const unsigned short* __restrict__ A, const unsigned short* __restrict__ BT,
             CT* __restrict__ C, const float* __restrict__ fc, const float* __restrict__ fs,
             int M, int N, int K, int ldc) {
    __shared__ unsigned short As[128 * 64];
    __shared__ unsigned short Bs[128 * 64];
    const int tid = threadIdx.x;
    const int wid = tid >> 6, lane = tid & 63;
    const int l31 = lane & 31, h2 = lane >> 5;
    const int brow = blockIdx.y * 128, bcol = blockIdx.x * 128;
    const int wr = wid >> 1, wc = wid & 1;      // 2x2 waves, 64x64 each
    f32x16 acc[2][2] = {};

    for (int kt = 0; kt < K; kt += 64) {
#pragma unroll
        for (int i = 0; i < 4; ++i) {           // A,B tiles: 1024 chunks of 16B each
            int c = i * 256 + tid;
            int row = c >> 3, u = c & 7;
            gload16(A + (size_t)(brow + row) * K + kt + ((u ^ (row & 7)) << 3),
                    As + (size_t)c * 8);
            gload16(BT + (size_t)(bcol + row) * K + kt + ((u ^ (row & 7)) << 3),
                    Bs + (size_t)c * 8);
        }
        __syncthreads();
        s8v a[2][4], b[2][4];                    // [frag][kstep of 16]
#pragma unroll
        for (int mm = 0; mm < 2; ++mm) {
            int row = wr * 64 + mm * 32 + l31;
#pragma unroll
            for (int ks = 0; ks < 4; ++ks)
                a[mm][ks] = *(const s8v*)(As + (size_t)row * 64 +
                                          (((2 * ks + h2) ^ (row & 7)) << 3));
        }
#pragma unroll
        for (int nn = 0; nn < 2; ++nn) {
            int row = wc * 64 + nn * 32 + l31;
#pragma unroll
            for (int ks = 0; ks < 4; ++ks)
                b[nn][ks] = *(const s8v*)(Bs + (size_t)row * 64 +
                                          (((2 * ks + h2) ^ (row & 7)) << 3));
        }
#pragma unroll
        for (int ks = 0; ks < 4; ++ks)
#pragma unroll
            for (int mm = 0; mm < 2; ++mm)
#pragma unroll
                for (int nn = 0; nn < 2; ++nn)
                    acc[mm][nn] = __builtin_amdgcn_mfma_f32_32x32x16_bf16(
                        a[mm][ks], b[nn][ks], acc[mm][nn], 0, 0, 0);
        __syncthreads();
    }
    // epilogue: D row (A idx) = mm*32 + (reg&3)+8*(reg>>2)+4*h2, D col (B idx) = nn*32+l31
#pragma unroll
    for (int mm = 0; mm < 2; ++mm)
#pragma unroll
        for (int nn = 0; nn < 2; ++nn)
#pragma unroll
            for (int reg = 0; reg < 16; ++reg) {
                int r = brow + wr * 64 + mm * 32 + (reg & 3) + 8 * (reg >> 2) + 4 * h2;
                int c = bcol + wc * 64 + nn * 32 + l31;
                float v = acc[mm][nn][reg];
                if constexpr (ROPE) {
                    // q cols [0,2048), k cols [2048,2560): rotate pairs (c even, c+1)
                    float vp = __shfl_xor(v, 1);
                    if (c < 2560) {
                        int fi = ((r & 2047) << 6) + ((c & 127) >> 1);
                        float cs = fc[fi], sn = fs[fi];
                        v = (l31 & 1) ? (vp * sn + v * cs) : (v * cs - vp * sn);
                    }
                }
                if constexpr (std::is_same<CT, float>::value)
                    C[(size_t)r * ldc + c] = v;
                else
                    C[(size_t)r * ldc + c] = f2bf(v);
            }
}

// ---------- Flash attention, GQA, causal — 32x32 MFMA, LDS-staged KV, lane-local softmax --
// 512 blocks x 256 threads (4 waves). blockIdx&7 = (b,kvh) -> XCD-pinned KV (1MB/XCD L2).
// The 4 waves are the 4 q-heads sharing this kvh: ONE staged K/V tile feeds 4 heads.
// qi = 63 - (bid>>3): measured-best mapping (R7 post-mortem: the "balanced pairing"
// alternative regressed 105.6->125 us; dispatch order is undefined, keep what measures best).
// Each wave owns 32 q rows (q = qw + lane&31); swapped 32x32 QK^T keeps q lane-local
// (softmax/rescale/normalize lane-local; P->B-frag = 16 cvt_pk + 8 shfl_xor(32)).
// K and V^T staged via coalesced global_load_lds, both-sides XOR swizzle (rule 21)
// -> conflict-free ds_read_b128 fragment reads. KVBLK=64 double-buffered (64KB LDS).
__global__ __launch_bounds__(256)
void attn_kernel(const unsigned short* __restrict__ qkv,
                 const unsigned short* __restrict__ vtg,
                 unsigned short* __restrict__ out) {
    constexpr int S = 2048;
    __shared__ unsigned short Ks[2][64 * 128];   // [key][d-unit8 ^ (key&7)]
    __shared__ unsigned short Vs[2][128 * 64];   // [d][key-unit8 ^ (d&7)]
    const int tid = threadIdx.x, lane = tid & 63, wid = tid >> 6;
    const int l31 = lane & 31, h2 = lane >> 5;
    const int lsw = l31 & 7;
    const int g8 = blockIdx.x & 7;               // (b,kvh) -> XCD pin
    const int b = g8 >> 2, kvh = g8 & 3;
    const int qi = 63 - (blockIdx.x >> 3);       // measured-best (round 6) ordering
    const int h = kvh * 4 + wid;                 // wave = head
    const int qw = qi * 32;
    const int qq = qw + l31;                     // this lane's q row
    const size_t rs = 3072;
    const float rscale = 0.08838834764831845f;   // 1/sqrt(128)

    const unsigned short* Qp = qkv + (size_t)(b * S + qw) * rs + h * 128 + h2 * 8;
    const unsigned short* Kbase = qkv + (size_t)(b * S) * rs + 2048 + kvh * 128;
    const unsigned short* Vtg = vtg + (size_t)((b * 4 + kvh) * 128) * S;

    // Q B-frag: col=q=l31, k = 16*kk + 8*h2 + e  (scattered, but once per kernel)
    s8v qf[8];
#pragma unroll
    for (int kk = 0; kk < 8; ++kk)
        qf[kk] = *(const s8v*)(Qp + (size_t)l31 * rs + kk * 16);

    f32x16 acc[4] = {};                          // out^T: acc[dblk], row d, col q
    float m_run = -1e30f, l_run = 0.f;
    const int nt = (qi >> 1) + 1;

    auto stage = [&](int t, int bufi) {
        const int kb64 = t * 64;
#pragma unroll
        for (int i = 0; i < 4; ++i) {            // K tile [64][128]: 1024 chunks of 16B
            int c = i * 256 + tid;
            int key = c >> 4, d8 = c & 15;
            gload16(Kbase + (size_t)(kb64 + key) * rs + ((d8 ^ (key & 7)) << 3),
                    &Ks[bufi][(size_t)c * 8]);
        }
#pragma unroll
        for (int i = 0; i < 4; ++i) {            // V^T tile [128][64]
            int c = i * 256 + tid;
            int d = c >> 3, k8 = c & 7;
            gload16(Vtg + (size_t)d * S + kb64 + ((k8 ^ (d & 7)) << 3),
                    &Vs[bufi][(size_t)c * 8]);
        }
    };

    int cur = 0;
    stage(0, 0);
    __syncthreads();

    for (int t = 0; t < nt; ++t) {
        if (t + 1 < nt) stage(t + 1, cur ^ 1);
        const int kb64 = t * 64;
        const char* Kb = (const char*)&Ks[cur][0];
        const char* Vb = (const char*)&Vs[cur][0];

        // ---- K A-frags from LDS (row=key, k=16kk+8h2+e); conflict-free swizzled ----
        s8v kf0[8], kf1[8];
#pragma unroll
        for (int kk = 0; kk < 8; ++kk)
            kf0[kk] = *(const s8v*)(Kb + l31 * 256 + (((2 * kk + h2) ^ lsw) << 4));
#pragma unroll
        for (int kk = 0; kk < 8; ++kk)
            kf1[kk] = *(const s8v*)(Kb + (32 + l31) * 256 + (((2 * kk + h2) ^ lsw) << 4));
        // ---- V^T A-frags (row=d=32dblk+l31, k=key=16kb+8h2+e) ----
        s8v vf[4][4];
#pragma unroll
        for (int kb = 0; kb < 4; ++kb)
#pragma unroll
            for (int dblk = 0; dblk < 4; ++dblk)
                vf[kb][dblk] = *(const s8v*)(Vb + (32 * dblk + l31) * 128 +
                                             (((2 * kb + h2) ^ lsw) << 4));

        // ---- QK^T (swapped): S^T[key][q], C col = q lane-local ----
        f32x16 sacc0 = {}, sacc1 = {};
        __builtin_amdgcn_s_setprio(1);
#pragma unroll
        for (int kk = 0; kk < 8; ++kk)
            sacc0 = __builtin_amdgcn_mfma_f32_32x32x16_bf16(kf0[kk], qf[kk], sacc0, 0, 0, 0);
#pragma unroll
        for (int kk = 0; kk < 8; ++kk)
            sacc1 = __builtin_amdgcn_mfma_f32_32x32x16_bf16(kf1[kk], qf[kk], sacc1, 0, 0, 0);
        __builtin_amdgcn_s_setprio(0);

        // ---- mask + scale: lane holds S[key(r,g)][q=qq] ----
        float sv[32];
#pragma unroll
        for (int g = 0; g < 2; ++g)
#pragma unroll
            for (int r = 0; r < 16; ++r) {
                int key = kb64 + 32 * g + (r & 3) + 8 * (r >> 2) + 4 * h2;
                float s = (g ? sacc1[r] : sacc0[r]) * rscale;
                sv[g * 16 + r] = (key <= qq) ? s : -1e30f;
            }

        // ---- online softmax, q lane-local; defer-max (THR=8) ----
        float mx = sv[0];
#pragma unroll
        for (int i = 1; i < 32; ++i) mx = fmaxf(mx, sv[i]);
        mx = fmaxf(mx, __shfl_xor(mx, 32));
        if (!__all(mx - m_run <= 8.f)) {
            float mn = fmaxf(m_run, mx);
            float alpha = __expf(m_run - mn);
            m_run = mn;
            l_run *= alpha;
#pragma unroll
            for (int dblk = 0; dblk < 4; ++dblk)
#pragma unroll
                for (int r = 0; r < 16; ++r) acc[dblk][r] *= alpha;
        }
        float ps = 0.f;
#pragma unroll
        for (int i = 0; i < 32; ++i) {
            float e = __expf(sv[i] - m_run);
            sv[i] = e;
            ps += e;
        }
        ps += __shfl_xor(ps, 32);
        l_run += ps;

        // ---- P -> B-frag (col=q, k=key): cvt_pk pairs + lane^32 exchange ----
        unsigned int pw[4][4];
#pragma unroll
        for (int g = 0; g < 2; ++g) {
            unsigned int w[8];
#pragma unroll
            for (int j = 0; j < 8; ++j)
                w[j] = cvtpk(sv[g * 16 + 2 * j], sv[g * 16 + 2 * j + 1]);
#pragma unroll
            for (int u = 0; u < 2; ++u) {
                unsigned int t0 = (unsigned)__shfl_xor((int)w[4 * u + 0], 32);
                unsigned int t1 = (unsigned)__shfl_xor((int)w[4 * u + 1], 32);
                unsigned int t2 = (unsigned)__shfl_xor((int)w[4 * u + 2], 32);
                unsigned int t3 = (unsigned)__shfl_xor((int)w[4 * u + 3], 32);
                pw[2 * g + u][0] = h2 ? t2 : w[4 * u + 0];
                pw[2 * g + u][1] = h2 ? t3 : w[4 * u + 1];
                pw[2 * g + u][2] = h2 ? w[4 * u + 2] : t0;
                pw[2 * g + u][3] = h2 ? w[4 * u + 3] : t1;
            }
        }

        // ---- PV: out^T[d][q] += V^T(32d x 16k) * P^T(16k x 32q) ----
        __builtin_amdgcn_s_setprio(1);
#pragma unroll
        for (int kb = 0; kb < 4; ++kb) {
            u32x4 wv;
            wv[0] = pw[kb][0]; wv[1] = pw[kb][1]; wv[2] = pw[kb][2]; wv[3] = pw[kb][3];
            s8v pf = __builtin_bit_cast(s8v, wv);
#pragma unroll
            for (int dblk = 0; dblk < 4; ++dblk)
                acc[dblk] = __builtin_amdgcn_mfma_f32_32x32x16_bf16(vf[kb][dblk], pf, acc[dblk], 0, 0, 0);
        }
        __builtin_amdgcn_s_setprio(0);

        __syncthreads();
        cur ^= 1;
    }

    // ---- normalize (lane-local) and store out[q][h*128+d] ----
    float inv = 1.f / l_run;
    unsigned short* Op = out + (size_t)(b * S + qq) * 2048 + h * 128 + 4 * h2;
#pragma unroll
    for (int dblk = 0; dblk < 4; ++dblk)
#pragma unroll
        for (int s = 0; s < 4; ++s) {
            u32x2 wv;
            wv[0] = cvtpk(acc[dblk][4 * s + 0] * inv, acc[dblk][4 * s + 1] * inv);
            wv[1] = cvtpk(acc[dblk][4 * s + 2] * inv, acc[dblk][4 * s + 3] * inv);
            *(u32x2*)(Op + 32 * dblk + 8 * s) = wv;
        }
}

// ---------- launch ----------
extern "C" void kernel_launch(void* const* d_in, const int* in_sizes, int n_in,
                              void* d_out, int out_size, void* d_ws, size_t ws_size,
                              hipStream_t stream) {
    const float* x  = (const float*)d_in[0];
    const float* fc = (const float*)d_in[1];
    const float* fs = (const float*)d_in[2];
    const float* wq = (const float*)d_in[4];
    const float* wk = (const float*)d_in[5];
    const float* wv = (const float*)d_in[6];
    const float* wo = (const float*)d_in[7];
    float* out = (float*)d_out;

    char* ws = (char*)d_ws;
    unsigned short* xb    = (unsigned short*)ws;                               // 16 MB (reused as attn out)
    unsigned short* wqkvT = (unsigned short*)(ws + 16777216);                  // 12 MB (reused as V^T)
    unsigned short* woT   = (unsigned short*)(ws + 16777216 + 12582912);       // 8 MB
    unsigned short* qkvb  = (unsigned short*)(ws + 16777216 + 12582912 + 8388608); // 24 MB
    unsigned short* attnb = xb;
    unsigned short* vtb   = wqkvT;      // V^T [2][4][128][2048] = 4 MB, lives after gemm1

    conv_bf16<<<4096, 256, 0, stream>>>(x, xb, 1048576);
    dim3 tb(32, 8);
    transpose_conv_qkv<<<dim3(96, 64), tb, 0, stream>>>(wq, wk, wv, wqkvT);
    transpose_conv<<<dim3(64, 64), tb, 0, stream>>>(wo, woT, 2048, 2048);
    // gemm1 with fused RoPE on q/k columns (c < 2560)
    gemm_bt<unsigned short, true><<<dim3(24, 32), 256, 0, stream>>>(
        xb, wqkvT, qkvb, fc, fs, 4096, 3072, 2048, 3072);
    vtrans<<<dim3(128, 16), tb, 0, stream>>>(qkvb, vtb);
    attn_kernel<<<512, 256, 0, stream>>>(qkvb, vtb, attnb);
    gemm_bt<float, false><<<dim3(16, 32), 256, 0, stream>>>(
        attnb, woT, out, nullptr, nullptr, 4096, 2048, 2048, 2048);
}